// Round 9
// baseline (268.271 us; speedup 1.0000x reference)
//
#include <hip/hip_runtime.h>
#include <hip/hip_bf16.h>
#include <hip/hip_cooperative_groups.h>
#include <stdint.h>

namespace cg = cooperative_groups;

#define BB 4
#define NN 2048
#define FF 128
#define JS 8

typedef __attribute__((ext_vector_type(8))) short bf16x8;
typedef __attribute__((ext_vector_type(4))) float f32x4;

__device__ inline unsigned pk_bf16(float a, float b) {
    union { float f; unsigned u; } x, y;
    x.f = a; y.f = b;
    unsigned xu = x.u + (0x7fffu + ((x.u >> 16) & 1u));
    unsigned yu = y.u + (0x7fffu + ((y.u >> 16) & 1u));
    return (xu >> 16) | (yu & 0xffff0000u);
}

#define XT_P 136
#define WT_P 136

struct SmemP1 {
    uint16_t xt[32 * XT_P];
    uint16_t Wt[128 * WT_P];
    float sredw[2][64];
};
struct SmemP2 {
    float Opw[8][16 * 68];
    float rsw[4][16];
};
union Smem { SmemP1 p1; SmemP2 p2; };

// One cooperative kernel, 256 blocks x 512 thr (8 waves), 1 block/CU resident.
// Phase 1: h = x@W (bf16 MFMA), s = h@a_w + a_b, Ht[b][g][n] bf16.
// Phase 2: split-K fused scores+softmax+P@H; 16 rounds, depth-2 A prefetch.
// Phase 3: reduce 8 j-slices, normalize, +bias.
__global__ __launch_bounds__(512, 2) void fused_gat(
    const float* __restrict__ x, const float* __restrict__ A,
    const float* __restrict__ W, const float* __restrict__ a_w,
    const float* __restrict__ a_b, const float* __restrict__ bias,
    uint16_t* __restrict__ Ht, float* __restrict__ s,
    uint16_t* __restrict__ po, float* __restrict__ prs,
    float* __restrict__ out)
{
    __shared__ Smem sm;
    cg::grid_group grid = cg::this_grid();

    const int t = threadIdx.x;
    const int w = t >> 6, l = t & 63;
    const int m16 = l & 15, q = l >> 4;
    const int bx = blockIdx.x;

    // ================= Phase 1: projection =================
    {
        const int b = bx >> 6;
        const int n0 = (bx & 63) << 5;

        // batch-load W (each thread: 8 k-rows x 4 g-cols)
        const int c4 = (t & 31) * 4, kseg = (t >> 5) * 8;
        float4 wr[8];
        #pragma unroll
        for (int kk = 0; kk < 8; ++kk)
            wr[kk] = *(const float4*)(W + (size_t)(kseg + kk) * 128 + c4);

        // stage x-tile (32 rows) as bf16
        const int xrow = t >> 4, xc0 = (t & 15) * 8;
        const float* xr = x + ((size_t)(b * NN + n0 + xrow)) * FF + xc0;
        const float4 v0 = *(const float4*)xr;
        const float4 v1 = *(const float4*)(xr + 4);
        {
            unsigned* dst = (unsigned*)(sm.p1.xt + xrow * XT_P + xc0);
            dst[0] = pk_bf16(v0.x, v0.y); dst[1] = pk_bf16(v0.z, v0.w);
            dst[2] = pk_bf16(v1.x, v1.y); dst[3] = pk_bf16(v1.z, v1.w);
        }
        // write W^T bf16
        #pragma unroll
        for (int i = 0; i < 4; ++i) {
            unsigned* wd = (unsigned*)(sm.p1.Wt + (c4 + i) * WT_P + kseg);
            wd[0] = pk_bf16(((const float*)&wr[0])[i], ((const float*)&wr[1])[i]);
            wd[1] = pk_bf16(((const float*)&wr[2])[i], ((const float*)&wr[3])[i]);
            wd[2] = pk_bf16(((const float*)&wr[4])[i], ((const float*)&wr[5])[i]);
            wd[3] = pk_bf16(((const float*)&wr[6])[i], ((const float*)&wr[7])[i]);
        }
        const int rg = w >> 2, ws2 = w & 3;     // row-group, g-pair wave
        const int g0 = (2 * ws2) * 16 + m16, g1 = (2 * ws2 + 1) * 16 + m16;
        const float aw0 = a_w[g0], aw1 = a_w[g1];
        __syncthreads();

        f32x4 acc0 = {}, acc1 = {};
        #pragma unroll
        for (int dk = 0; dk < 4; ++dk) {
            bf16x8 af = *(const bf16x8*)(sm.p1.xt + (rg * 16 + m16) * XT_P + dk * 32 + q * 8);
            bf16x8 b0 = *(const bf16x8*)(sm.p1.Wt + g0 * WT_P + dk * 32 + q * 8);
            bf16x8 b1 = *(const bf16x8*)(sm.p1.Wt + g1 * WT_P + dk * 32 + q * 8);
            acc0 = __builtin_amdgcn_mfma_f32_16x16x32_bf16(af, b0, acc0, 0, 0, 0);
            acc1 = __builtin_amdgcn_mfma_f32_16x16x32_bf16(af, b1, acc1, 0, 0, 0);
        }
        float sp[4];
        #pragma unroll
        for (int r = 0; r < 4; ++r) sp[r] = acc0[r] * aw0 + acc1[r] * aw1;
        #pragma unroll
        for (int off = 1; off < 16; off <<= 1)
            #pragma unroll
            for (int r = 0; r < 4; ++r) sp[r] += __shfl_xor(sp[r], off, 64);
        if (m16 == 0) {
            #pragma unroll
            for (int r = 0; r < 4; ++r) sm.p1.sredw[rg][ws2 * 16 + q * 4 + r] = sp[r];
        }
        {
            uint2 o0 = { pk_bf16(acc0[0], acc0[1]), pk_bf16(acc0[2], acc0[3]) };
            uint2 o1 = { pk_bf16(acc1[0], acc1[1]), pk_bf16(acc1[2], acc1[3]) };
            const int nb = n0 + rg * 16 + q * 4;
            *(uint2*)(Ht + ((size_t)(b * FF + g0)) * NN + nb) = o0;
            *(uint2*)(Ht + ((size_t)(b * FF + g1)) * NN + nb) = o1;
        }
        __syncthreads();
        if (t < 32) {
            const int rg2 = t >> 4, row = t & 15;
            s[b * NN + n0 + rg2 * 16 + row] =
                sm.p1.sredw[rg2][row] + sm.p1.sredw[rg2][16 + row] +
                sm.p1.sredw[rg2][32 + row] + sm.p1.sredw[rg2][48 + row] + a_b[0];
        }
    }

    __threadfence();
    grid.sync();

    // ================= Phase 2: split-K attention =================
    {
        const int gh = w & 1, jh = w >> 1;
        const int js = bx & 7;
        const int is = (bx >> 3) & 7;
        const int b  = bx >> 6;
        const int j0 = js * 256;
        const int ibase = is * 256;

        const float* sb = s + b * NN;
        const float* Ab = A + (size_t)b * NN * NN;
        const uint16_t* Hb = Ht + (size_t)b * FF * NN;

        const int jcb = j0 + jh * 64;
        const int jq0 = jcb + q * 8;
        const int jq1 = jcb + 32 + q * 8;

        float4 sj0 = *(const float4*)(sb + jq0);
        float4 sj1 = *(const float4*)(sb + jq0 + 4);
        float4 sj2 = *(const float4*)(sb + jq1);
        float4 sj3 = *(const float4*)(sb + jq1 + 4);

        bf16x8 hf[4][2];
        #pragma unroll
        for (int gt = 0; gt < 4; ++gt) {
            const uint16_t* hp = Hb + (size_t)(gh * 64 + gt * 16 + m16) * NN;
            hf[gt][0] = *(const bf16x8*)(hp + jq0);
            hf[gt][1] = *(const bf16x8*)(hp + jq1);
        }

        // depth-2 A prefetch
        const float* ArP = Ab + (size_t)(ibase + m16) * NN;
        float4 p0 = *(const float4*)(ArP + jq0);
        float4 p1 = *(const float4*)(ArP + jq0 + 4);
        float4 p2 = *(const float4*)(ArP + jq1);
        float4 p3 = *(const float4*)(ArP + jq1 + 4);
        float siP = sb[ibase + m16];
        const float* ArQ = Ab + (size_t)(ibase + 16 + m16) * NN;
        float4 q0 = *(const float4*)(ArQ + jq0);
        float4 q1 = *(const float4*)(ArQ + jq0 + 4);
        float4 q2 = *(const float4*)(ArQ + jq1);
        float4 q3 = *(const float4*)(ArQ + jq1 + 4);
        float siQ = sb[ibase + 16 + m16];

        const size_t slice = (size_t)(js * BB + b);

        for (int r = 0; r < 16; ++r) {
            const int i0r = ibase + r * 16;
            const int i0n = ibase + ((r + 2) & 15) * 16;

            const float* An = Ab + (size_t)(i0n + m16) * NN;
            float4 n0_ = *(const float4*)(An + jq0);
            float4 n1_ = *(const float4*)(An + jq0 + 4);
            float4 n2_ = *(const float4*)(An + jq1);
            float4 n3_ = *(const float4*)(An + jq1 + 4);
            const float siN = sb[i0n + m16];

            const float svv[16] = {sj0.x,sj0.y,sj0.z,sj0.w, sj1.x,sj1.y,sj1.z,sj1.w,
                                   sj2.x,sj2.y,sj2.z,sj2.w, sj3.x,sj3.y,sj3.z,sj3.w};
            const float avv[16] = {p0.x,p0.y,p0.z,p0.w, p1.x,p1.y,p1.z,p1.w,
                                   p2.x,p2.y,p2.z,p2.w, p3.x,p3.y,p3.z,p3.w};
            float pv[16]; float rs = 0.f;
            #pragma unroll
            for (int j = 0; j < 16; ++j) {
                float e = siP + svv[j];
                e = fmaxf(e, 0.2f * e);               // LeakyReLU(0.2)
                pv[j] = __expf(e + avv[j]);
                rs += pv[j];
            }
            union { unsigned u[4]; bf16x8 v; } fa0, fa1;
            #pragma unroll
            for (int j = 0; j < 4; ++j) {
                fa0.u[j] = pk_bf16(pv[2 * j], pv[2 * j + 1]);
                fa1.u[j] = pk_bf16(pv[8 + 2 * j], pv[9 + 2 * j]);
            }

            f32x4 acc[4];
            #pragma unroll
            for (int gt = 0; gt < 4; ++gt) {
                f32x4 z = {0.f, 0.f, 0.f, 0.f};
                z = __builtin_amdgcn_mfma_f32_16x16x32_bf16(fa0.v, hf[gt][0], z, 0, 0, 0);
                acc[gt] = __builtin_amdgcn_mfma_f32_16x16x32_bf16(fa1.v, hf[gt][1], z, 0, 0, 0);
            }

            rs += __shfl_xor(rs, 16, 64);
            rs += __shfl_xor(rs, 32, 64);
            if (gh == 0 && q == 0) sm.p2.rsw[jh][m16] = rs;

            #pragma unroll
            for (int gt = 0; gt < 4; ++gt)
                #pragma unroll
                for (int rr = 0; rr < 4; ++rr)
                    sm.p2.Opw[w][(q * 4 + rr) * 68 + gt * 16 + m16] = acc[gt][rr];
            asm volatile("s_waitcnt lgkmcnt(0)\n\ts_barrier" ::: "memory");

            {
                const int row = t >> 5;
                const int c4p = (t & 31) * 4;
                const int gh2 = c4p >> 6;
                const int cc = c4p & 63;
                float4 v = {0.f, 0.f, 0.f, 0.f};
                #pragma unroll
                for (int jh2 = 0; jh2 < 4; ++jh2) {
                    float4 u = *(const float4*)&sm.p2.Opw[jh2 * 2 + gh2][row * 68 + cc];
                    v.x += u.x; v.y += u.y; v.z += u.z; v.w += u.w;
                }
                unsigned* op = (unsigned*)(po + ((slice * NN + i0r + row) * FF + c4p));
                op[0] = pk_bf16(v.x, v.y);
                op[1] = pk_bf16(v.z, v.w);
                if (t < 16)
                    prs[slice * NN + i0r + t] = sm.p2.rsw[0][t] + sm.p2.rsw[1][t] +
                                                sm.p2.rsw[2][t] + sm.p2.rsw[3][t];
            }
            asm volatile("s_waitcnt lgkmcnt(0)\n\ts_barrier" ::: "memory");

            p0 = q0; p1 = q1; p2 = q2; p3 = q3; siP = siQ;
            q0 = n0_; q1 = n1_; q2 = n2_; q3 = n3_; siQ = siN;
        }
    }

    __threadfence();
    grid.sync();

    // ================= Phase 3: reduce + normalize + bias =================
    {
        #pragma unroll
        for (int it = 0; it < 2; ++it) {
            const int idx = it * 131072 + bx * 512 + t;
            const int g4 = (idx & 31) * 4;
            const int i = (idx >> 5) & (NN - 1);
            const int b = idx >> 16;
            float v0 = 0.f, v1 = 0.f, v2 = 0.f, v3 = 0.f, rsum = 0.f;
            #pragma unroll
            for (int js2 = 0; js2 < JS; ++js2) {
                const size_t base = (size_t)(js2 * BB + b) * NN + i;
                uint2 u = *(const uint2*)(po + base * FF + g4);
                union { unsigned u; float f; } c0, c1, c2, c3;
                c0.u = u.x << 16; c1.u = u.x & 0xffff0000u;
                c2.u = u.y << 16; c3.u = u.y & 0xffff0000u;
                v0 += c0.f; v1 += c1.f; v2 += c2.f; v3 += c3.f;
                rsum += prs[base];
            }
            const float inv = 1.0f / rsum;
            float4 bv = *(const float4*)(bias + g4);
            float4 o = { v0 * inv + bv.x, v1 * inv + bv.y, v2 * inv + bv.z, v3 * inv + bv.w };
            *(float4*)(out + ((size_t)b * NN + i) * FF + g4) = o;
        }
    }
}

extern "C" void kernel_launch(void* const* d_in, const int* in_sizes, int n_in,
                              void* d_out, int out_size, void* d_ws, size_t ws_size,
                              hipStream_t stream) {
    const float* x    = (const float*)d_in[0];
    const float* A    = (const float*)d_in[1];
    const float* W    = (const float*)d_in[2];
    const float* a_w  = (const float*)d_in[3];
    const float* a_b  = (const float*)d_in[4];
    const float* bias = (const float*)d_in[5];
    float* out = (float*)d_out;

    char* ws = (char*)d_ws;
    uint16_t* Ht = (uint16_t*)ws;                                  // 2 MB
    float* s = (float*)(ws + 2 * 1024 * 1024);                     // 64 KB slot
    uint16_t* po = (uint16_t*)(ws + 2 * 1024 * 1024 + 65536);      // 16.8 MB
    float* prs = (float*)(ws + 2 * 1024 * 1024 + 65536 + (size_t)JS * BB * NN * FF * 2);  // 256 KB

    void* args[] = { (void*)&x, (void*)&A, (void*)&W, (void*)&a_w, (void*)&a_b,
                     (void*)&bias, (void*)&Ht, (void*)&s, (void*)&po, (void*)&prs,
                     (void*)&out };
    hipLaunchCooperativeKernel((void*)fused_gat, dim3(256), dim3(512), args, 0, stream);
}